// Round 5
// baseline (319.076 us; speedup 1.0000x reference)
//
#include <hip/hip_runtime.h>
#include <hip/hip_bf16.h>

// ---------------------------------------------------------------------------
// Fused MHA forward: x@Wq/Wk/Wv -> heads -> softmax(QK^T/sqrt(dk))V -> @Wo
// B=2, S=2048, D=1024, H=16, Dk=64.  All matmuls via bf16 MFMA, fp32 accum.
// ---------------------------------------------------------------------------

#define SEQ 2048
#define DMODEL 1024
#define NHEAD 16
#define DK 64
#define NBATCH 2
#define NBH 32
#define MTOT 4096

typedef __attribute__((ext_vector_type(4))) float  f32x4;
typedef __attribute__((ext_vector_type(8))) short  bf16x8;
typedef __attribute__((ext_vector_type(4))) short  bf16x4;
typedef __attribute__((ext_vector_type(4))) unsigned short u16x4;

// scale folded into Q: (1/sqrt(64)) * log2(e) so softmax can use exp2
#define QSCALE 0.18033688f

// bf16 convert via scalar cast -> compiler emits v_cvt_pk_bf16_f32 (m240)
__device__ __forceinline__ unsigned short f2bf(float x) {
  union { __hip_bfloat16 h; unsigned short u; } cv;
  cv.h = __float2bfloat16(x);
  return cv.u;
}

#define EXP2(x) __builtin_amdgcn_exp2f(x)

__device__ __forceinline__ float fmax3(float a, float b, float c) {
  return fmaxf(fmaxf(a, b), c);  // clang fuses to v_max3_f32
}

__device__ __forceinline__ void gload16(const void* g, void* l) {
  __builtin_amdgcn_global_load_lds(
      (const __attribute__((address_space(1))) unsigned int*)g,
      (__attribute__((address_space(3))) unsigned int*)l, 16, 0, 0);
}

// ---------------------------------------------------------------------------
// conv_all: blocks [0,1024) transpose W0..W3 (fp32->bf16, W[k][n]->Wt[n][k]);
//           blocks [1024,2048) convert x fp32->bf16 (16 elems/thread).
// ---------------------------------------------------------------------------
__global__ __launch_bounds__(256) void conv_all(
    const float* __restrict__ X, unsigned short* __restrict__ Xb,
    const float* __restrict__ W0, const float* __restrict__ W1,
    const float* __restrict__ W2, const float* __restrict__ W3,
    unsigned short* __restrict__ T0, unsigned short* __restrict__ T1,
    unsigned short* __restrict__ T2, unsigned short* __restrict__ T3) {
  __shared__ float tile[64][65];
  const int b = blockIdx.x;
  if (b >= 1024) {
    size_t i = ((size_t)(b - 1024) * 256 + threadIdx.x) * 16;
#pragma unroll
    for (int c = 0; c < 4; ++c) {
      f32x4 v = *(const f32x4*)&X[i + c * 4];
      u16x4 pk;
      pk[0] = f2bf(v[0]); pk[1] = f2bf(v[1]);
      pk[2] = f2bf(v[2]); pk[3] = f2bf(v[3]);
      *(u16x4*)&Xb[i + c * 4] = pk;
    }
    return;
  }
  const int z = b >> 8, rem = b & 255;
  const float* W; unsigned short* T;
  switch (z) {
    case 0: W = W0; T = T0; break;
    case 1: W = W1; T = T1; break;
    case 2: W = W2; T = T2; break;
    default: W = W3; T = T3; break;
  }
  const int k0 = (rem & 15) * 64, n0 = (rem >> 4) * 64;
  const int tr = threadIdx.x >> 4, tc = (threadIdx.x & 15) * 4;
#pragma unroll
  for (int i = 0; i < 4; ++i) {
    int r = tr + i * 16;
    f32x4 v = *(const f32x4*)&W[(size_t)(k0 + r) * DMODEL + n0 + tc];
    tile[r][tc + 0] = v[0]; tile[r][tc + 1] = v[1];
    tile[r][tc + 2] = v[2]; tile[r][tc + 3] = v[3];
  }
  __syncthreads();
#pragma unroll
  for (int i = 0; i < 4; ++i) {
    int nr = tr + i * 16;
    u16x4 pk;
    pk[0] = f2bf(tile[tc + 0][nr]); pk[1] = f2bf(tile[tc + 1][nr]);
    pk[2] = f2bf(tile[tc + 2][nr]); pk[3] = f2bf(tile[tc + 3][nr]);
    *(u16x4*)&T[(size_t)(n0 + nr) * DMODEL + k0 + tc] = pk;
  }
}

// ---------------------------------------------------------------------------
// gemm_qkv: fused GEMM over N=3072 (Q|K|V).  grid (24,32).
// ---------------------------------------------------------------------------
__global__ __launch_bounds__(256) void gemm_qkv(
    const short* __restrict__ A, const short* __restrict__ Bt,
    const float* __restrict__ bq, const float* __restrict__ bk,
    const float* __restrict__ bv, unsigned short* __restrict__ Qg,
    unsigned short* __restrict__ Kg, unsigned short* __restrict__ Vtg) {
  const int tid = threadIdx.x;
  const int lane = tid & 63, w = tid >> 6;
  const int lq = lane & 15, g = lane >> 4;
  const int m0 = blockIdx.y * 128, n0 = blockIdx.x * 128;
  const int wm = (w >> 1) * 64, wn = (w & 1) * 64;
  const int which = n0 >> 10;

  __shared__ __attribute__((aligned(16))) short abuf[128 * 64];
  __shared__ __attribute__((aligned(16))) short bbuf[128 * 64];

  f32x4 acc[4][4] = {};
  const char* Ab = (const char*)A;
  const char* Bb = (const char*)Bt;

  for (int kt = 0; kt < 16; ++kt) {
    __syncthreads();
#pragma unroll
    for (int i = 0; i < 4; ++i) {
      int y = tid * 16 + i * 4096;
      int row = y >> 7, cb = y & 127;
      gload16(Ab + (size_t)(m0 + row) * 2048 + kt * 128 + cb, (char*)abuf + y);
      gload16(Bb + (size_t)(n0 + row) * 2048 + kt * 128 + cb, (char*)bbuf + y);
    }
    __syncthreads();
#pragma unroll
    for (int ks = 0; ks < 2; ++ks) {
      bf16x8 af[4], bfr[4];
#pragma unroll
      for (int i = 0; i < 4; ++i) {
        af[i]  = *(const bf16x8*)&abuf[(wm + i * 16 + lq) * 64 + ks * 32 + g * 8];
        bfr[i] = *(const bf16x8*)&bbuf[(wn + i * 16 + lq) * 64 + ks * 32 + g * 8];
      }
#pragma unroll
      for (int mi = 0; mi < 4; ++mi)
#pragma unroll
        for (int ni = 0; ni < 4; ++ni)
          acc[mi][ni] = __builtin_amdgcn_mfma_f32_16x16x32_bf16(
              af[mi], bfr[ni], acc[mi][ni], 0, 0, 0);
    }
  }

  const float* bias = (which == 0) ? bq : (which == 1) ? bk : bv;
  unsigned short* o = (which == 0) ? Qg : (which == 1) ? Kg : Vtg;
  const float sc = (which == 0) ? QSCALE : 1.0f;

#pragma unroll
  for (int mi = 0; mi < 4; ++mi) {
#pragma unroll
    for (int ni = 0; ni < 4; ++ni) {
      const int nl = (n0 & 1023) + wn + ni * 16 + lq;
      const int mbase = m0 + wm + mi * 16 + g * 4;
      const float bs = bias[nl];
      const int h = nl >> 6, d = nl & 63;
      if (which == 2) {
        const int b = mbase >> 11, s = mbase & 2047;
        u16x4 pk;
#pragma unroll
        for (int r = 0; r < 4; ++r) pk[r] = f2bf(acc[mi][ni][r] + bs);
        *(u16x4*)&o[(size_t)((b * NHEAD + h) * DK + d) * SEQ + s] = pk;
      } else {
#pragma unroll
        for (int r = 0; r < 4; ++r) {
          const int m = mbase + r;
          const int b = m >> 11, s = m & 2047;
          o[(size_t)((b * NHEAD + h) * SEQ + s) * DK + d] =
              f2bf((acc[mi][ni][r] + bs) * sc);
        }
      }
    }
  }
}

// ---------------------------------------------------------------------------
// gemm_out: final projection, fp32 out.  grid (8,32).
// ---------------------------------------------------------------------------
__global__ __launch_bounds__(256) void gemm_out(const short* __restrict__ A,
                                                const short* __restrict__ Bt,
                                                const float* __restrict__ bias,
                                                float* __restrict__ o) {
  const int tid = threadIdx.x;
  const int lane = tid & 63, w = tid >> 6;
  const int lq = lane & 15, g = lane >> 4;
  const int m0 = blockIdx.y * 128, n0 = blockIdx.x * 128;
  const int wm = (w >> 1) * 64, wn = (w & 1) * 64;

  __shared__ __attribute__((aligned(16))) short abuf[128 * 64];
  __shared__ __attribute__((aligned(16))) short bbuf[128 * 64];

  f32x4 acc[4][4] = {};
  const char* Ab = (const char*)A;
  const char* Bb = (const char*)Bt;

  for (int kt = 0; kt < 16; ++kt) {
    __syncthreads();
#pragma unroll
    for (int i = 0; i < 4; ++i) {
      int y = tid * 16 + i * 4096;
      int row = y >> 7, cb = y & 127;
      gload16(Ab + (size_t)(m0 + row) * 2048 + kt * 128 + cb, (char*)abuf + y);
      gload16(Bb + (size_t)(n0 + row) * 2048 + kt * 128 + cb, (char*)bbuf + y);
    }
    __syncthreads();
#pragma unroll
    for (int ks = 0; ks < 2; ++ks) {
      bf16x8 af[4], bfr[4];
#pragma unroll
      for (int i = 0; i < 4; ++i) {
        af[i]  = *(const bf16x8*)&abuf[(wm + i * 16 + lq) * 64 + ks * 32 + g * 8];
        bfr[i] = *(const bf16x8*)&bbuf[(wn + i * 16 + lq) * 64 + ks * 32 + g * 8];
      }
#pragma unroll
      for (int mi = 0; mi < 4; ++mi)
#pragma unroll
        for (int ni = 0; ni < 4; ++ni)
          acc[mi][ni] = __builtin_amdgcn_mfma_f32_16x16x32_bf16(
              af[mi], bfr[ni], acc[mi][ni], 0, 0, 0);
    }
  }

#pragma unroll
  for (int mi = 0; mi < 4; ++mi) {
#pragma unroll
    for (int ni = 0; ni < 4; ++ni) {
      const int n = n0 + wn + ni * 16 + lq;
      const int mbase = m0 + wm + mi * 16 + g * 4;
      const float bs = bias[n];
#pragma unroll
      for (int r = 0; r < 4; ++r)
        o[(size_t)(mbase + r) * DMODEL + n] = acc[mi][ni][r] + bs;
    }
  }
}

// ---------------------------------------------------------------------------
// attn: flash attention, barrier-free.  K/V read DIRECTLY from global
// (L2-resident: XCD-chunked swizzle keeps 4 heads = 2MB per XCD L2).
// grid 1024 blocks, 256 thr, 4 independent waves x 16 q rows.
// l computed via ones-row MFMA against the P fragment (no VALU psum reduce).
// ---------------------------------------------------------------------------
__global__ __launch_bounds__(256) void attn_kernel(
    const short* __restrict__ Qg, const short* __restrict__ Kg,
    const short* __restrict__ Vtg, unsigned short* __restrict__ Og) {
  const int tid = threadIdx.x, lane = tid & 63, w = tid >> 6;
  const int lq = lane & 15, g = lane >> 4;
  // bijective XCD-chunk swizzle (1024 % 8 == 0): XCD x owns heads 4x..4x+3
  const int bid = blockIdx.x;
  const int swz = (bid & 7) * 128 + (bid >> 3);
  const int bh = swz >> 5, q0 = (swz & 31) * 64;

  __shared__ __attribute__((aligned(16))) short pbuf[4 * 1024];  // 2KB/wave

  const short* qrow = Qg + ((size_t)bh * SEQ + q0 + w * 16 + lq) * DK;
  bf16x8 qf[2];
  qf[0] = *(const bf16x8*)&qrow[g * 8];
  qf[1] = *(const bf16x8*)&qrow[32 + g * 8];

  bf16x8 ones;
#pragma unroll
  for (int j = 0; j < 8; ++j) ones[j] = (short)0x3F80;  // bf16 1.0

  f32x4 oacc[4] = {};
  float m_run = -3.0e38f, l_run = 0.f;

  const short* kp = Kg + (size_t)bh * SEQ * DK + lq * DK + g * 8;
  const short* vp = Vtg + (size_t)bh * DK * SEQ + lq * SEQ + g * 8;
  const int sw = (lq & 7) << 4;
  char* pb = (char*)pbuf + w * 2048 + lq * 128;

  for (int t = 0; t < 32; ++t) {
    const short* kt_p = kp + t * 64 * DK;
    const short* vt_p = vp + t * 64;

    // ---- K fragments (global, L2) then QK^T: S^T = K . Q^T
    bf16x8 kf[4][2];
#pragma unroll
    for (int kt2 = 0; kt2 < 4; ++kt2)
#pragma unroll
      for (int ks = 0; ks < 2; ++ks)
        kf[kt2][ks] = *(const bf16x8*)&kt_p[kt2 * 16 * DK + ks * 32];

    f32x4 sv[4];
    __builtin_amdgcn_s_setprio(1);
#pragma unroll
    for (int kt2 = 0; kt2 < 4; ++kt2) {
      f32x4 s = {};
      s = __builtin_amdgcn_mfma_f32_16x16x32_bf16(kf[kt2][0], qf[0], s, 0, 0, 0);
      s = __builtin_amdgcn_mfma_f32_16x16x32_bf16(kf[kt2][1], qf[1], s, 0, 0, 0);
      sv[kt2] = s;
    }
    __builtin_amdgcn_s_setprio(0);

    // ---- online softmax with defer-max (THR=8, log2 domain)
    float m0a = fmax3(sv[0][0], sv[0][1], sv[0][2]);
    float m1a = fmax3(sv[0][3], sv[1][0], sv[1][1]);
    float m2a = fmax3(sv[1][2], sv[1][3], sv[2][0]);
    float m3a = fmax3(sv[2][1], sv[2][2], sv[2][3]);
    float m4a = fmax3(sv[3][0], sv[3][1], sv[3][2]);
    float vmax = fmaxf(fmax3(m0a, m1a, m2a), fmax3(m3a, m4a, sv[3][3]));
    vmax = fmaxf(vmax, __shfl_xor(vmax, 16));
    vmax = fmaxf(vmax, __shfl_xor(vmax, 32));

    if (!__all(vmax <= m_run + 8.0f)) {
      const float m_new = fmaxf(m_run, vmax);
      const float corr = EXP2(m_run - m_new);
#pragma unroll
      for (int dt = 0; dt < 4; ++dt)
#pragma unroll
        for (int r = 0; r < 4; ++r) oacc[dt][r] *= corr;
      l_run *= corr;
      m_run = m_new;
    }

#pragma unroll
    for (int kt2 = 0; kt2 < 4; ++kt2)
#pragma unroll
      for (int r = 0; r < 4; ++r) sv[kt2][r] = EXP2(sv[kt2][r] - m_run);

    // ---- P -> per-wave LDS (swizzled; same-wave round trip, no barrier)
#pragma unroll
    for (int kt2 = 0; kt2 < 4; ++kt2) {
      bf16x4 pk;
#pragma unroll
      for (int r = 0; r < 4; ++r) pk[r] = (short)f2bf(sv[kt2][r]);
      *(bf16x4*)(pb + ((kt2 * 32 + g * 8) ^ sw)) = pk;
    }
    asm volatile("" ::: "memory");

    // ---- PV: out^T[d][q] += V^T[d][k] * P^T[k][q];  l via ones-row MFMA
    f32x4 lsum = {};
    __builtin_amdgcn_s_setprio(1);
#pragma unroll
    for (int ks2 = 0; ks2 < 2; ++ks2) {
      bf16x8 pf = *(const bf16x8*)(pb + ((ks2 * 64 + g * 16) ^ sw));
      lsum = __builtin_amdgcn_mfma_f32_16x16x32_bf16(ones, pf, lsum, 0, 0, 0);
#pragma unroll
      for (int dt = 0; dt < 4; ++dt) {
        bf16x8 vf = *(const bf16x8*)&vt_p[dt * 16 * SEQ + ks2 * 32];
        oacc[dt] = __builtin_amdgcn_mfma_f32_16x16x32_bf16(vf, pf, oacc[dt], 0, 0, 0);
      }
    }
    __builtin_amdgcn_s_setprio(0);
    l_run += lsum[0];
  }

  // ---- epilogue: divide by l, write bf16 [b][s][h*64+d]
  const float inv = 1.0f / l_run;
  const int b = bh >> 4, h = bh & 15;
  const size_t rowbase =
      ((size_t)b * SEQ + q0 + w * 16 + lq) * DMODEL + h * DK;
#pragma unroll
  for (int dt = 0; dt < 4; ++dt) {
    u16x4 pk;
#pragma unroll
    for (int r = 0; r < 4; ++r) pk[r] = f2bf(oacc[dt][r] * inv);
    *(u16x4*)&Og[rowbase + dt * 16 + g * 4] = pk;
  }
}

// ---------------------------------------------------------------------------
// launch
// ---------------------------------------------------------------------------
extern "C" void kernel_launch(void* const* d_in, const int* in_sizes, int n_in,
                              void* d_out, int out_size, void* d_ws,
                              size_t ws_size, hipStream_t stream) {
  const float* x  = (const float*)d_in[0];
  const float* Wq = (const float*)d_in[1];
  const float* bq = (const float*)d_in[2];
  const float* Wk = (const float*)d_in[3];
  const float* bk = (const float*)d_in[4];
  const float* Wv = (const float*)d_in[5];
  const float* bv = (const float*)d_in[6];
  const float* Wo = (const float*)d_in[7];
  const float* bo = (const float*)d_in[8];
  float* out = (float*)d_out;

  char* ws = (char*)d_ws;
  unsigned short* Xb    = (unsigned short*)(ws);                 // 8 MB
  unsigned short* Wtqkv = (unsigned short*)(ws + (8u << 20));    // 6 MB
  unsigned short* Wto   = (unsigned short*)(ws + (14u << 20));   // 2 MB
  unsigned short* Qg    = (unsigned short*)(ws + (16u << 20));   // 8 MB
  unsigned short* Kg    = (unsigned short*)(ws + (24u << 20));   // 8 MB
  unsigned short* Vtg   = (unsigned short*)(ws + (32u << 20));   // 8 MB
  unsigned short* Ab    = Xb;  // reuse Xb region after QKV GEMM reads it

  conv_all<<<dim3(2048), 256, 0, stream>>>(
      x, Xb, Wq, Wk, Wv, Wo,
      Wtqkv, Wtqkv + (1u << 20), Wtqkv + (2u << 20), Wto);

  gemm_qkv<<<dim3(24, 32), 256, 0, stream>>>(
      (const short*)Xb, (const short*)Wtqkv, bq, bk, bv, Qg, Kg, Vtg);

  attn_kernel<<<dim3(1024), 256, 0, stream>>>(
      (const short*)Qg, (const short*)Kg, (const short*)Vtg, Ab);

  gemm_out<<<dim3(8, 32), 256, 0, stream>>>(
      (const short*)Ab, (const short*)Wto, bo, out);
}

// Round 7
// 148.202 us; speedup vs baseline: 2.1530x; 2.1530x over previous
//
#include <hip/hip_runtime.h>
#include <hip/hip_bf16.h>

// ---------------------------------------------------------------------------
// Fused MHA forward: x@Wq/Wk/Wv -> heads -> softmax(QK^T/sqrt(dk))V -> @Wo
// B=2, S=2048, D=1024, H=16, Dk=64.  All matmuls via bf16 MFMA, fp32 accum.
// ---------------------------------------------------------------------------

#define SEQ 2048
#define DMODEL 1024
#define NHEAD 16
#define DK 64
#define NBATCH 2
#define NBH 32
#define MTOT 4096

typedef __attribute__((ext_vector_type(4))) float  f32x4;
typedef __attribute__((ext_vector_type(8))) short  bf16x8;
typedef __attribute__((ext_vector_type(4))) short  bf16x4;
typedef __attribute__((ext_vector_type(4))) unsigned short u16x4;

// scale folded into Q: (1/sqrt(64)) * log2(e) so softmax can use exp2
#define QSCALE 0.18033688f

// bf16 convert via scalar cast -> compiler emits v_cvt_pk_bf16_f32 (m240)
__device__ __forceinline__ unsigned short f2bf(float x) {
  union { __hip_bfloat16 h; unsigned short u; } cv;
  cv.h = __float2bfloat16(x);
  return cv.u;
}

#define EXP2(x) __builtin_amdgcn_exp2f(x)

__device__ __forceinline__ float fmax3(float a, float b, float c) {
  return fmaxf(fmaxf(a, b), c);  // clang fuses to v_max3_f32
}

__device__ __forceinline__ void gload16(const void* g, void* l) {
  __builtin_amdgcn_global_load_lds(
      (const __attribute__((address_space(1))) unsigned int*)g,
      (__attribute__((address_space(3))) unsigned int*)l, 16, 0, 0);
}

// ---------------------------------------------------------------------------
// conv_all: blocks [0,1024) transpose W0..W3 (fp32->bf16, W[k][n]->Wt[n][k]);
//           blocks [1024,2048) convert x fp32->bf16 (16 elems/thread).
// ---------------------------------------------------------------------------
__global__ __launch_bounds__(256) void conv_all(
    const float* __restrict__ X, unsigned short* __restrict__ Xb,
    const float* __restrict__ W0, const float* __restrict__ W1,
    const float* __restrict__ W2, const float* __restrict__ W3,
    unsigned short* __restrict__ T0, unsigned short* __restrict__ T1,
    unsigned short* __restrict__ T2, unsigned short* __restrict__ T3) {
  __shared__ float tile[64][65];
  const int b = blockIdx.x;
  if (b >= 1024) {
    size_t i = ((size_t)(b - 1024) * 256 + threadIdx.x) * 16;
#pragma unroll
    for (int c = 0; c < 4; ++c) {
      f32x4 v = *(const f32x4*)&X[i + c * 4];
      u16x4 pk;
      pk[0] = f2bf(v[0]); pk[1] = f2bf(v[1]);
      pk[2] = f2bf(v[2]); pk[3] = f2bf(v[3]);
      *(u16x4*)&Xb[i + c * 4] = pk;
    }
    return;
  }
  const int z = b >> 8, rem = b & 255;
  const float* W; unsigned short* T;
  switch (z) {
    case 0: W = W0; T = T0; break;
    case 1: W = W1; T = T1; break;
    case 2: W = W2; T = T2; break;
    default: W = W3; T = T3; break;
  }
  const int k0 = (rem & 15) * 64, n0 = (rem >> 4) * 64;
  const int tr = threadIdx.x >> 4, tc = (threadIdx.x & 15) * 4;
#pragma unroll
  for (int i = 0; i < 4; ++i) {
    int r = tr + i * 16;
    f32x4 v = *(const f32x4*)&W[(size_t)(k0 + r) * DMODEL + n0 + tc];
    tile[r][tc + 0] = v[0]; tile[r][tc + 1] = v[1];
    tile[r][tc + 2] = v[2]; tile[r][tc + 3] = v[3];
  }
  __syncthreads();
#pragma unroll
  for (int i = 0; i < 4; ++i) {
    int nr = tr + i * 16;
    u16x4 pk;
    pk[0] = f2bf(tile[tc + 0][nr]); pk[1] = f2bf(tile[tc + 1][nr]);
    pk[2] = f2bf(tile[tc + 2][nr]); pk[3] = f2bf(tile[tc + 3][nr]);
    *(u16x4*)&T[(size_t)(n0 + nr) * DMODEL + k0 + tc] = pk;
  }
}

// ---------------------------------------------------------------------------
// gemm_qkv: fused GEMM over N=3072 (Q|K|V).  grid (24,32).
// ---------------------------------------------------------------------------
__global__ __launch_bounds__(256) void gemm_qkv(
    const short* __restrict__ A, const short* __restrict__ Bt,
    const float* __restrict__ bq, const float* __restrict__ bk,
    const float* __restrict__ bv, unsigned short* __restrict__ Qg,
    unsigned short* __restrict__ Kg, unsigned short* __restrict__ Vtg) {
  const int tid = threadIdx.x;
  const int lane = tid & 63, w = tid >> 6;
  const int lq = lane & 15, g = lane >> 4;
  const int m0 = blockIdx.y * 128, n0 = blockIdx.x * 128;
  const int wm = (w >> 1) * 64, wn = (w & 1) * 64;
  const int which = n0 >> 10;

  __shared__ __attribute__((aligned(16))) short abuf[128 * 64];
  __shared__ __attribute__((aligned(16))) short bbuf[128 * 64];

  f32x4 acc[4][4] = {};
  const char* Ab = (const char*)A;
  const char* Bb = (const char*)Bt;

  for (int kt = 0; kt < 16; ++kt) {
    __syncthreads();
#pragma unroll
    for (int i = 0; i < 4; ++i) {
      int y = tid * 16 + i * 4096;
      int row = y >> 7, cb = y & 127;
      gload16(Ab + (size_t)(m0 + row) * 2048 + kt * 128 + cb, (char*)abuf + y);
      gload16(Bb + (size_t)(n0 + row) * 2048 + kt * 128 + cb, (char*)bbuf + y);
    }
    __syncthreads();
#pragma unroll
    for (int ks = 0; ks < 2; ++ks) {
      bf16x8 af[4], bfr[4];
#pragma unroll
      for (int i = 0; i < 4; ++i) {
        af[i]  = *(const bf16x8*)&abuf[(wm + i * 16 + lq) * 64 + ks * 32 + g * 8];
        bfr[i] = *(const bf16x8*)&bbuf[(wn + i * 16 + lq) * 64 + ks * 32 + g * 8];
      }
#pragma unroll
      for (int mi = 0; mi < 4; ++mi)
#pragma unroll
        for (int ni = 0; ni < 4; ++ni)
          acc[mi][ni] = __builtin_amdgcn_mfma_f32_16x16x32_bf16(
              af[mi], bfr[ni], acc[mi][ni], 0, 0, 0);
    }
  }

  const float* bias = (which == 0) ? bq : (which == 1) ? bk : bv;
  unsigned short* o = (which == 0) ? Qg : (which == 1) ? Kg : Vtg;
  const float sc = (which == 0) ? QSCALE : 1.0f;

#pragma unroll
  for (int mi = 0; mi < 4; ++mi) {
#pragma unroll
    for (int ni = 0; ni < 4; ++ni) {
      const int nl = (n0 & 1023) + wn + ni * 16 + lq;
      const int mbase = m0 + wm + mi * 16 + g * 4;
      const float bs = bias[nl];
      const int h = nl >> 6, d = nl & 63;
      if (which == 2) {
        const int b = mbase >> 11, s = mbase & 2047;
        u16x4 pk;
#pragma unroll
        for (int r = 0; r < 4; ++r) pk[r] = f2bf(acc[mi][ni][r] + bs);
        *(u16x4*)&o[(size_t)((b * NHEAD + h) * DK + d) * SEQ + s] = pk;
      } else {
#pragma unroll
        for (int r = 0; r < 4; ++r) {
          const int m = mbase + r;
          const int b = m >> 11, s = m & 2047;
          o[(size_t)((b * NHEAD + h) * SEQ + s) * DK + d] =
              f2bf((acc[mi][ni][r] + bs) * sc);
        }
      }
    }
  }
}

// ---------------------------------------------------------------------------
// gemm_out: final projection, fp32 out.  grid (8,32).
// ---------------------------------------------------------------------------
__global__ __launch_bounds__(256) void gemm_out(const short* __restrict__ A,
                                                const short* __restrict__ Bt,
                                                const float* __restrict__ bias,
                                                float* __restrict__ o) {
  const int tid = threadIdx.x;
  const int lane = tid & 63, w = tid >> 6;
  const int lq = lane & 15, g = lane >> 4;
  const int m0 = blockIdx.y * 128, n0 = blockIdx.x * 128;
  const int wm = (w >> 1) * 64, wn = (w & 1) * 64;

  __shared__ __attribute__((aligned(16))) short abuf[128 * 64];
  __shared__ __attribute__((aligned(16))) short bbuf[128 * 64];

  f32x4 acc[4][4] = {};
  const char* Ab = (const char*)A;
  const char* Bb = (const char*)Bt;

  for (int kt = 0; kt < 16; ++kt) {
    __syncthreads();
#pragma unroll
    for (int i = 0; i < 4; ++i) {
      int y = tid * 16 + i * 4096;
      int row = y >> 7, cb = y & 127;
      gload16(Ab + (size_t)(m0 + row) * 2048 + kt * 128 + cb, (char*)abuf + y);
      gload16(Bb + (size_t)(n0 + row) * 2048 + kt * 128 + cb, (char*)bbuf + y);
    }
    __syncthreads();
#pragma unroll
    for (int ks = 0; ks < 2; ++ks) {
      bf16x8 af[4], bfr[4];
#pragma unroll
      for (int i = 0; i < 4; ++i) {
        af[i]  = *(const bf16x8*)&abuf[(wm + i * 16 + lq) * 64 + ks * 32 + g * 8];
        bfr[i] = *(const bf16x8*)&bbuf[(wn + i * 16 + lq) * 64 + ks * 32 + g * 8];
      }
#pragma unroll
      for (int mi = 0; mi < 4; ++mi)
#pragma unroll
        for (int ni = 0; ni < 4; ++ni)
          acc[mi][ni] = __builtin_amdgcn_mfma_f32_16x16x32_bf16(
              af[mi], bfr[ni], acc[mi][ni], 0, 0, 0);
    }
  }

#pragma unroll
  for (int mi = 0; mi < 4; ++mi) {
#pragma unroll
    for (int ni = 0; ni < 4; ++ni) {
      const int n = n0 + wn + ni * 16 + lq;
      const int mbase = m0 + wm + mi * 16 + g * 4;
      const float bs = bias[n];
#pragma unroll
      for (int r = 0; r < 4; ++r)
        o[(size_t)(mbase + r) * DMODEL + n] = acc[mi][ni][r] + bs;
    }
  }
}

// ---------------------------------------------------------------------------
// attn: flash attention, KBLK=64, double-buffered swizzled LDS staging
// (round-4 structure) + XCD-chunk block swizzle for L2-resident K/V
// (round-5 lesson: L2 residency works, but staging is still required for
// latency hiding).  grid 1024 (1D), 256 thr, 4 waves x 16 q rows.
// l via ones-row MFMA; max tree via v_max3.
// ---------------------------------------------------------------------------
__global__ __launch_bounds__(256) void attn_kernel(
    const short* __restrict__ Qg, const short* __restrict__ Kg,
    const short* __restrict__ Vtg, unsigned short* __restrict__ Og) {
  const int tid = threadIdx.x, lane = tid & 63, w = tid >> 6;
  const int lq = lane & 15, g = lane >> 4;
  // bijective XCD-chunk swizzle (1024 % 8 == 0): XCD x owns heads 4x..4x+3
  const int bid = blockIdx.x;
  const int swz = (bid & 7) * 128 + (bid >> 3);
  const int bh = swz >> 5, q0 = (swz & 31) * 64;

  __shared__ __attribute__((aligned(16))) short kbuf[2][64 * 64];
  __shared__ __attribute__((aligned(16))) short vbuf[2][64 * 64];
  __shared__ __attribute__((aligned(16))) short pbuf[4 * 1024];  // 2KB/wave

  const short* qrow = Qg + ((size_t)bh * SEQ + q0 + w * 16 + lq) * DK;
  bf16x8 qf[2];
  qf[0] = *(const bf16x8*)&qrow[g * 8];
  qf[1] = *(const bf16x8*)&qrow[32 + g * 8];

  bf16x8 ones;
#pragma unroll
  for (int j = 0; j < 8; ++j) ones[j] = (short)0x3F80;  // bf16 1.0

  f32x4 oacc[4] = {};
  float m_run = -3.0e38f, l_run = 0.f;

  const char* kbase = (const char*)(Kg + (size_t)bh * SEQ * DK);
  const char* vbase = (const char*)(Vtg + (size_t)bh * DK * SEQ);
  const int sw = (lq & 7) << 4;  // read-side XOR

  const int y0 = tid * 16, y1 = y0 + 4096;
  const int r0 = y0 >> 7, r1 = y1 >> 7;
  const int c0 = (y0 ^ (r0 << 4)) & 0x70;
  const int c1 = (y1 ^ (r1 << 4)) & 0x70;
  const int ksrc0 = (y0 & ~0x70) | c0;
  const int ksrc1 = (y1 & ~0x70) | c1;
  const int vsrc0 = r0 * 4096 + c0;
  const int vsrc1 = r1 * 4096 + c1;

#define STAGE(T, BI)                                                      \
  do {                                                                    \
    gload16(kbase + (size_t)(T) * 8192 + ksrc0, (char*)kbuf[BI] + y0);    \
    gload16(kbase + (size_t)(T) * 8192 + ksrc1, (char*)kbuf[BI] + y1);    \
    gload16(vbase + vsrc0 + (size_t)(T) * 128, (char*)vbuf[BI] + y0);     \
    gload16(vbase + vsrc1 + (size_t)(T) * 128, (char*)vbuf[BI] + y1);     \
  } while (0)

  STAGE(0, 0);

  for (int t = 0; t < 32; ++t) {
    const int bi = t & 1;
    __syncthreads();
    if (t < 31) STAGE(t + 1, bi ^ 1);

    const char* kb = (const char*)kbuf[bi];
    const char* vb = (const char*)vbuf[bi];

    // ---- S^T = K . Q^T
    f32x4 sv[4];
    __builtin_amdgcn_s_setprio(1);
#pragma unroll
    for (int kt2 = 0; kt2 < 4; ++kt2) {
      f32x4 s = {};
#pragma unroll
      for (int ks = 0; ks < 2; ++ks) {
        bf16x8 kf = *(const bf16x8*)(kb + (kt2 * 16 + lq) * 128 +
                                     ((ks * 64 + g * 16) ^ sw));
        s = __builtin_amdgcn_mfma_f32_16x16x32_bf16(kf, qf[ks], s, 0, 0, 0);
      }
      sv[kt2] = s;
    }
    __builtin_amdgcn_s_setprio(0);

    // ---- online softmax with defer-max (THR=8, log2 domain), v_max3 tree
    float m0a = fmax3(sv[0][0], sv[0][1], sv[0][2]);
    float m1a = fmax3(sv[0][3], sv[1][0], sv[1][1]);
    float m2a = fmax3(sv[1][2], sv[1][3], sv[2][0]);
    float m3a = fmax3(sv[2][1], sv[2][2], sv[2][3]);
    float m4a = fmax3(sv[3][0], sv[3][1], sv[3][2]);
    float vmax = fmaxf(fmax3(m0a, m1a, m2a), fmax3(m3a, m4a, sv[3][3]));
    vmax = fmaxf(vmax, __shfl_xor(vmax, 16));
    vmax = fmaxf(vmax, __shfl_xor(vmax, 32));

    if (!__all(vmax <= m_run + 8.0f)) {
      const float m_new = fmaxf(m_run, vmax);
      const float corr = EXP2(m_run - m_new);
#pragma unroll
      for (int dt = 0; dt < 4; ++dt)
#pragma unroll
        for (int r = 0; r < 4; ++r) oacc[dt][r] *= corr;
      l_run *= corr;
      m_run = m_new;
    }

#pragma unroll
    for (int kt2 = 0; kt2 < 4; ++kt2)
#pragma unroll
      for (int r = 0; r < 4; ++r) sv[kt2][r] = EXP2(sv[kt2][r] - m_run);

    // ---- P -> per-wave LDS (swizzled; same-wave round trip, no barrier)
    char* pb = (char*)pbuf + w * 2048 + lq * 128;
#pragma unroll
    for (int kt2 = 0; kt2 < 4; ++kt2) {
      bf16x4 pk;
#pragma unroll
      for (int r = 0; r < 4; ++r) pk[r] = (short)f2bf(sv[kt2][r]);
      *(bf16x4*)(pb + ((kt2 * 32 + g * 8) ^ sw)) = pk;
    }
    asm volatile("" ::: "memory");

    // ---- PV: out^T[d][q] += V^T[d][k] * P^T[k][q];  l via ones-row MFMA
    f32x4 lsum = {};
    __builtin_amdgcn_s_setprio(1);
#pragma unroll
    for (int ks2 = 0; ks2 < 2; ++ks2) {
      bf16x8 pf = *(const bf16x8*)(pb + ((ks2 * 64 + g * 16) ^ sw));
      lsum = __builtin_amdgcn_mfma_f32_16x16x32_bf16(ones, pf, lsum, 0, 0, 0);
#pragma unroll
      for (int dt = 0; dt < 4; ++dt) {
        bf16x8 vf = *(const bf16x8*)(vb + (dt * 16 + lq) * 128 +
                                     ((ks2 * 64 + g * 16) ^ sw));
        oacc[dt] = __builtin_amdgcn_mfma_f32_16x16x32_bf16(vf, pf, oacc[dt], 0, 0, 0);
      }
    }
    __builtin_amdgcn_s_setprio(0);
    l_run += lsum[0];
  }
#undef STAGE

  // ---- epilogue: divide by l, write bf16 [b][s][h*64+d]
  const float inv = 1.0f / l_run;
  const int b = bh >> 4, h = bh & 15;
  const size_t rowbase =
      ((size_t)b * SEQ + q0 + w * 16 + lq) * DMODEL + h * DK;
#pragma unroll
  for (int dt = 0; dt < 4; ++dt) {
    u16x4 pk;
#pragma unroll
    for (int r = 0; r < 4; ++r) pk[r] = f2bf(oacc[dt][r] * inv);
    *(u16x4*)&Og[rowbase + dt * 16 + g * 4] = pk;
  }
}

// ---------------------------------------------------------------------------
// launch
// ---------------------------------------------------------------------------
extern "C" void kernel_launch(void* const* d_in, const int* in_sizes, int n_in,
                              void* d_out, int out_size, void* d_ws,
                              size_t ws_size, hipStream_t stream) {
  const float* x  = (const float*)d_in[0];
  const float* Wq = (const float*)d_in[1];
  const float* bq = (const float*)d_in[2];
  const float* Wk = (const float*)d_in[3];
  const float* bk = (const float*)d_in[4];
  const float* Wv = (const float*)d_in[5];
  const float* bv = (const float*)d_in[6];
  const float* Wo = (const float*)d_in[7];
  const float* bo = (const float*)d_in[8];
  float* out = (float*)d_out;

  char* ws = (char*)d_ws;
  unsigned short* Xb    = (unsigned short*)(ws);                 // 8 MB
  unsigned short* Wtqkv = (unsigned short*)(ws + (8u << 20));    // 6 MB
  unsigned short* Wto   = (unsigned short*)(ws + (14u << 20));   // 2 MB
  unsigned short* Qg    = (unsigned short*)(ws + (16u << 20));   // 8 MB
  unsigned short* Kg    = (unsigned short*)(ws + (24u << 20));   // 8 MB
  unsigned short* Vtg   = (unsigned short*)(ws + (32u << 20));   // 8 MB
  unsigned short* Ab    = Xb;  // reuse Xb region after QKV GEMM reads it

  conv_all<<<dim3(2048), 256, 0, stream>>>(
      x, Xb, Wq, Wk, Wv, Wo,
      Wtqkv, Wtqkv + (1u << 20), Wtqkv + (2u << 20), Wto);

  gemm_qkv<<<dim3(24, 32), 256, 0, stream>>>(
      (const short*)Xb, (const short*)Wtqkv, bq, bk, bv, Qg, Kg, Vtg);

  attn_kernel<<<dim3(1024), 256, 0, stream>>>(
      (const short*)Qg, (const short*)Kg, (const short*)Vtg, Ab);

  gemm_out<<<dim3(8, 32), 256, 0, stream>>>(
      (const short*)Ab, (const short*)Wto, bo, out);
}